// Round 1
// baseline (2159.545 us; speedup 1.0000x reference)
//
#include <hip/hip_runtime.h>
#include <math.h>

#define N_NODES 50000
#define N_EDGES 600000
#define N_GRAPHS 512
#define F_IN 128
#define D_HID 128
#define EDIM 384

static __device__ __forceinline__ float wave_reduce_sum(float s) {
#pragma unroll
  for (int off = 32; off > 0; off >>= 1) s += __shfl_xor(s, off, 64);
  return s;
}

// ---------------- graph preprocessing ----------------

__global__ void hist_kernel(const int* __restrict__ dst, int* __restrict__ cnt) {
  int i = blockIdx.x * blockDim.x + threadIdx.x;
  if (i < N_EDGES) atomicAdd(&cnt[dst[i]], 1);
}

__global__ void gptr_kernel(const int* __restrict__ batch, int* __restrict__ gptr) {
  int g = blockIdx.x * blockDim.x + threadIdx.x;
  if (g > N_GRAPHS) return;
  int lo = 0, hi = N_NODES;
  while (lo < hi) { int mid = (lo + hi) >> 1; if (batch[mid] < g) lo = mid + 1; else hi = mid; }
  gptr[g] = lo;
}

__global__ __launch_bounds__(1024) void scan_kernel(const int* __restrict__ cnt,
                                                    int* __restrict__ row_ptr,
                                                    int* __restrict__ cursor) {
  __shared__ int wsum[16];
  int tid = threadIdx.x, lane = tid & 63, wid = tid >> 6;
  int carry = 0;
  for (int base = 0; base < N_NODES; base += 1024) {
    int idx = base + tid;
    int v = (idx < N_NODES) ? cnt[idx] : 0;
    int x = v;
#pragma unroll
    for (int off = 1; off < 64; off <<= 1) {
      int t = __shfl_up(x, off, 64);
      if (lane >= off) x += t;
    }
    if (lane == 63) wsum[wid] = x;
    __syncthreads();
    int wo = 0, tot = 0;
#pragma unroll
    for (int w = 0; w < 16; ++w) { int s = wsum[w]; tot += s; if (w < wid) wo += s; }
    int inc = x + wo + carry;
    if (idx < N_NODES) { row_ptr[idx + 1] = inc; cursor[idx] = inc - v; }
    carry += tot;
    __syncthreads();
  }
  if (tid == 0) row_ptr[0] = 0;
}

__global__ void dinv_kernel(const int* __restrict__ cnt, float* __restrict__ dinv) {
  int i = blockIdx.x * blockDim.x + threadIdx.x;
  if (i < N_NODES) dinv[i] = 1.0f / sqrtf((float)(cnt[i] + 1));
}

__global__ void scatter_kernel(const int* __restrict__ src, const int* __restrict__ dst,
                               const float* __restrict__ dinv, int* __restrict__ cursor,
                               int* __restrict__ col, float* __restrict__ ew) {
  int e = blockIdx.x * blockDim.x + threadIdx.x;
  if (e >= N_EDGES) return;
  int s = src[e], d = dst[e];
  int pos = atomicAdd(&cursor[d], 1);
  col[pos] = s;
  ew[pos] = dinv[s] * dinv[d];
}

// ---------------- logmap0 (wave per row of 128) ----------------

__global__ __launch_bounds__(256) void logmap_kernel(const float* __restrict__ x,
                                                     float* __restrict__ out) {
  int row = blockIdx.x * 4 + (threadIdx.x >> 6);
  int lane = threadIdx.x & 63;
  if (row >= N_NODES) return;
  float2 v = *(const float2*)(x + (size_t)row * F_IN + lane * 2);
  float s = wave_reduce_sum(v.x * v.x + v.y * v.y);
  float n = sqrtf(s);
  float nc = fmaxf(n, 1e-15f);
  float f = atanhf(fminf(nc, 0.9999999f)) / nc;
  float2 o; o.x = v.x * f; o.y = v.y * f;
  *(float2*)(out + (size_t)row * F_IN + lane * 2) = o;
}

// ---------------- generic fp32 tiled GEMM: C[N,M] = A[N,K] @ B[K,M] ----------------
// BM=64 rows, BN=128 cols, BK=32; 256 threads; 4x8 per-thread tile.

#define BM 64
#define BN 128
#define BK 32

__global__ __launch_bounds__(256) void gemm_kernel(const float* __restrict__ A, int lda,
                                                   const float* __restrict__ B, int M, int K,
                                                   int Nrows, const float* __restrict__ bias,
                                                   int do_relu, float* __restrict__ C) {
  __shared__ __align__(16) float As[BK][BM + 4];  // transposed: As[k][r]
  __shared__ __align__(16) float Bs[BK][BN + 4];
  int tid = threadIdx.x;
  int tx = tid & 15, ty = tid >> 4;
  int row0 = blockIdx.x * BM, col0 = blockIdx.y * BN;
  float acc[4][8] = {};
  for (int k0 = 0; k0 < K; k0 += BK) {
    {
      int r = tid >> 3;             // 0..31
      int kk = (tid & 7) << 2;      // 0,4,..,28
#pragma unroll
      for (int p = 0; p < 2; ++p) {
        int rr = r + p * 32;
        int gr = row0 + rr;
        float4 v = make_float4(0.f, 0.f, 0.f, 0.f);
        if (gr < Nrows) v = *(const float4*)(A + (size_t)gr * lda + k0 + kk);
        As[kk + 0][rr] = v.x; As[kk + 1][rr] = v.y; As[kk + 2][rr] = v.z; As[kk + 3][rr] = v.w;
      }
    }
    {
      int kb = tid >> 5;            // 0..7
      int c = (tid & 31) << 2;      // 0..124
#pragma unroll
      for (int p = 0; p < 4; ++p) {
        int k = kb + p * 8;
        *(float4*)&Bs[k][c] = *(const float4*)(B + (size_t)(k0 + k) * M + col0 + c);
      }
    }
    __syncthreads();
#pragma unroll
    for (int k = 0; k < BK; ++k) {
      float4 a = *(const float4*)&As[k][ty << 2];
      float4 b0 = *(const float4*)&Bs[k][tx << 3];
      float4 b1 = *(const float4*)&Bs[k][(tx << 3) + 4];
      float av[4] = {a.x, a.y, a.z, a.w};
      float bv[8] = {b0.x, b0.y, b0.z, b0.w, b1.x, b1.y, b1.z, b1.w};
#pragma unroll
      for (int i = 0; i < 4; ++i)
#pragma unroll
        for (int j = 0; j < 8; ++j) acc[i][j] = fmaf(av[i], bv[j], acc[i][j]);
    }
    __syncthreads();
  }
#pragma unroll
  for (int i = 0; i < 4; ++i) {
    int r = row0 + (ty << 2) + i;
    if (r < Nrows) {
#pragma unroll
      for (int j = 0; j < 8; ++j) {
        int c = col0 + (tx << 3) + j;
        float v = acc[i][j];
        if (bias) v += bias[c];
        if (do_relu) v = fmaxf(v, 0.0f);
        C[(size_t)r * M + c] = v;
      }
    }
  }
}

// ---------------- CSR aggregation + bias + relu (block of 128 = one node) ----------------

__global__ __launch_bounds__(128) void agg_kernel(const float* __restrict__ H,
                                                  const float* __restrict__ dinv,
                                                  const int* __restrict__ row_ptr,
                                                  const int* __restrict__ col,
                                                  const float* __restrict__ ew,
                                                  const float* __restrict__ bias,
                                                  float* __restrict__ out) {
  int i = blockIdx.x;
  int c = threadIdx.x;
  float di = dinv[i];
  float acc = H[(size_t)i * D_HID + c] * (di * di);
  int s = row_ptr[i], e = row_ptr[i + 1];
  int j = s;
  for (; j + 4 <= e; j += 4) {
    int c0 = col[j], c1 = col[j + 1], c2 = col[j + 2], c3 = col[j + 3];
    float w0 = ew[j], w1 = ew[j + 1], w2 = ew[j + 2], w3 = ew[j + 3];
    acc += H[(size_t)c0 * D_HID + c] * w0;
    acc += H[(size_t)c1 * D_HID + c] * w1;
    acc += H[(size_t)c2 * D_HID + c] * w2;
    acc += H[(size_t)c3 * D_HID + c] * w3;
  }
  for (; j < e; ++j) acc += H[(size_t)col[j] * D_HID + c] * ew[j];
  acc += bias[c];
  out[(size_t)i * EDIM + c] = fmaxf(acc, 0.0f);
}

// ---------------- global_add_pool over sorted batch ----------------

__global__ __launch_bounds__(384) void pool_kernel(const float* __restrict__ NB,
                                                   const int* __restrict__ gptr,
                                                   float* __restrict__ gcat_half) {
  int g = blockIdx.x, c = threadIdx.x;
  int s = gptr[g], e = gptr[g + 1];
  float acc = 0.0f;
  for (int i = s; i < e; ++i) acc += NB[(size_t)i * EDIM + c];
  gcat_half[(size_t)g * 768 + c] = acc;
}

// ---------------- expmap0 + proj, in-place on rows of 384 ----------------

__global__ __launch_bounds__(256) void exp_proj_kernel(float* __restrict__ y, int nrows) {
  int row = blockIdx.x * 4 + (threadIdx.x >> 6);
  int lane = threadIdx.x & 63;
  if (row >= nrows) return;
  float* p = y + (size_t)row * EDIM;
  float v[6];
  float s = 0.0f;
#pragma unroll
  for (int j = 0; j < 6; ++j) { v[j] = p[lane + j * 64]; s += v[j] * v[j]; }
  s = wave_reduce_sum(s);
  float n = fmaxf(sqrtf(s), 1e-15f);
  float th = tanhf(n);
  float f = th / n;
  float n2 = fmaxf(th, 1e-15f);
  const float maxn = 1.0f - 4e-3f;
  if (n2 > maxn) f *= maxn / n2;
#pragma unroll
  for (int j = 0; j < 6; ++j) p[lane + j * 64] = v[j] * f;
}

// ---------------- driver ----------------

extern "C" void kernel_launch(void* const* d_in, const int* in_sizes, int n_in,
                              void* d_out, int out_size, void* d_ws, size_t ws_size,
                              hipStream_t stream) {
  (void)in_sizes; (void)n_in; (void)out_size; (void)ws_size;
  const float* x   = (const float*)d_in[0];
  const float* x_s = (const float*)d_in[1];
  const int* src   = (const int*)d_in[2];
  const int* dst   = (const int*)d_in[3];
  const int* batch = (const int*)d_in[4];
  const float* Wf[3] = {(const float*)d_in[5], (const float*)d_in[6], (const float*)d_in[7]};
  const float* bf[3] = {(const float*)d_in[8], (const float*)d_in[9], (const float*)d_in[10]};
  const float* Wsb[3] = {(const float*)d_in[11], (const float*)d_in[12], (const float*)d_in[13]};
  const float* bs[3] = {(const float*)d_in[14], (const float*)d_in[15], (const float*)d_in[16]};
  const float* P1 = (const float*)d_in[17];
  const float* P2 = (const float*)d_in[18];
  const float* G1 = (const float*)d_in[19];
  const float* G2 = (const float*)d_in[20];
  float* out = (float*)d_out;

  char* w = (char*)d_ws;
  auto alloc = [&](size_t bytes) {
    char* p = w;
    w += (bytes + 255) & ~(size_t)255;
    return p;
  };
  float* A    = (float*)alloc((size_t)N_NODES * 128 * 4);
  float* H    = (float*)alloc((size_t)N_NODES * 128 * 4);
  float* NB   = (float*)alloc((size_t)N_NODES * 384 * 4);
  float* HID  = (float*)alloc((size_t)N_NODES * 384 * 4);
  int* cnt    = (int*)alloc((size_t)N_NODES * 4);
  int* row_ptr= (int*)alloc((size_t)(N_NODES + 1) * 4);
  int* cursor = (int*)alloc((size_t)N_NODES * 4);
  float* dinv = (float*)alloc((size_t)N_NODES * 4);
  int* col    = (int*)alloc((size_t)N_EDGES * 4);
  float* ew   = (float*)alloc((size_t)N_EDGES * 4);
  int* gptr   = (int*)alloc((size_t)(N_GRAPHS + 1) * 4);
  float* gcat = (float*)alloc((size_t)N_GRAPHS * 768 * 4);

  // ---- graph structure (shared by both branches, all layers) ----
  hipMemsetAsync(cnt, 0, (size_t)N_NODES * 4, stream);
  hist_kernel<<<(N_EDGES + 255) / 256, 256, 0, stream>>>(dst, cnt);
  gptr_kernel<<<(N_GRAPHS + 256) / 256, 256, 0, stream>>>(batch, gptr);
  scan_kernel<<<1, 1024, 0, stream>>>(cnt, row_ptr, cursor);
  dinv_kernel<<<(N_NODES + 255) / 256, 256, 0, stream>>>(cnt, dinv);
  scatter_kernel<<<(N_EDGES + 255) / 256, 256, 0, stream>>>(src, dst, dinv, cursor, col, ew);

  const size_t OUT0 = 0;
  const size_t OUT1 = (size_t)N_GRAPHS * EDIM;
  const size_t OUT2 = OUT1 + (size_t)N_GRAPHS * EDIM;
  const size_t OUT3 = OUT2 + (size_t)N_NODES * EDIM;
  const size_t OUT4 = OUT3 + (size_t)N_GRAPHS * EDIM;

  const int gx_nodes = (N_NODES + BM - 1) / BM;  // 782

  auto run_branch = [&](const float* xin, const float* const* Wb, const float* const* bb,
                        float* gcat_half, float* outp) {
    logmap_kernel<<<(N_NODES + 3) / 4, 256, 0, stream>>>(xin, A);
    const float* cur = A;
    int lda = 128;
    for (int l = 0; l < 3; ++l) {
      gemm_kernel<<<dim3(gx_nodes, 1), 256, 0, stream>>>(cur, lda, Wb[l], 128, 128, N_NODES,
                                                         nullptr, 0, H);
      agg_kernel<<<N_NODES, 128, 0, stream>>>(H, dinv, row_ptr, col, ew, bb[l], NB + l * 128);
      cur = NB + l * 128;
      lda = EDIM;
    }
    pool_kernel<<<N_GRAPHS, EDIM, 0, stream>>>(NB, gptr, gcat_half);
    gemm_kernel<<<dim3(gx_nodes, 3), 256, 0, stream>>>(NB, EDIM, P1, EDIM, EDIM, N_NODES,
                                                       nullptr, 1, HID);
    gemm_kernel<<<dim3(gx_nodes, 3), 256, 0, stream>>>(HID, EDIM, P2, EDIM, EDIM, N_NODES,
                                                       nullptr, 0, outp);
    exp_proj_kernel<<<(N_NODES + 3) / 4, 256, 0, stream>>>(outp, N_NODES);
  };

  run_branch(x, Wf, bf, gcat, out + OUT2);
  run_branch(x_s, Wsb, bs, gcat + EDIM, out + OUT4);

  float* GH = H;  // reuse [512,384] scratch
  const int gx_g = (N_GRAPHS + BM - 1) / BM;  // 8

  // g head: relu(gcat @ G1) @ G2 -> out0
  gemm_kernel<<<dim3(gx_g, 3), 256, 0, stream>>>(gcat, 768, G1, EDIM, 768, N_GRAPHS, nullptr, 1, GH);
  gemm_kernel<<<dim3(gx_g, 3), 256, 0, stream>>>(GH, EDIM, G2, EDIM, EDIM, N_GRAPHS, nullptr, 0, out + OUT0);
  exp_proj_kernel<<<(N_GRAPHS + 3) / 4, 256, 0, stream>>>(out + OUT0, N_GRAPHS);

  // g_f head -> out1
  gemm_kernel<<<dim3(gx_g, 3), 256, 0, stream>>>(gcat, 768, P1, EDIM, EDIM, N_GRAPHS, nullptr, 1, GH);
  gemm_kernel<<<dim3(gx_g, 3), 256, 0, stream>>>(GH, EDIM, P2, EDIM, EDIM, N_GRAPHS, nullptr, 0, out + OUT1);
  exp_proj_kernel<<<(N_GRAPHS + 3) / 4, 256, 0, stream>>>(out + OUT1, N_GRAPHS);

  // g_s head -> out3
  gemm_kernel<<<dim3(gx_g, 3), 256, 0, stream>>>(gcat + EDIM, 768, P1, EDIM, EDIM, N_GRAPHS, nullptr, 1, GH);
  gemm_kernel<<<dim3(gx_g, 3), 256, 0, stream>>>(GH, EDIM, P2, EDIM, EDIM, N_GRAPHS, nullptr, 0, out + OUT3);
  exp_proj_kernel<<<(N_GRAPHS + 3) / 4, 256, 0, stream>>>(out + OUT3, N_GRAPHS);
}

// Round 2
// 1414.674 us; speedup vs baseline: 1.5265x; 1.5265x over previous
//
#include <hip/hip_runtime.h>
#include <math.h>

#define N_NODES 50000
#define N_EDGES 600000
#define N_GRAPHS 512
#define F_IN 128
#define D_HID 128
#define EDIM 384

typedef __attribute__((ext_vector_type(8))) short bf16x8;
typedef __attribute__((ext_vector_type(4))) float f32x4;

static __device__ __forceinline__ float wave_reduce_sum(float s) {
#pragma unroll
  for (int off = 32; off > 0; off >>= 1) s += __shfl_xor(s, off, 64);
  return s;
}

static __device__ __forceinline__ short f2b(float f) {
  unsigned u = __float_as_uint(f);
  unsigned r = (u + 0x7FFFu + ((u >> 16) & 1u)) >> 16;
  return (short)r;
}

// ---------------- graph preprocessing ----------------

__global__ void hist_kernel(const int* __restrict__ dst, int* __restrict__ cnt) {
  int i = blockIdx.x * blockDim.x + threadIdx.x;
  if (i < N_EDGES) atomicAdd(&cnt[dst[i]], 1);
}

__global__ void gptr_kernel(const int* __restrict__ batch, int* __restrict__ gptr) {
  int g = blockIdx.x * blockDim.x + threadIdx.x;
  if (g > N_GRAPHS) return;
  int lo = 0, hi = N_NODES;
  while (lo < hi) { int mid = (lo + hi) >> 1; if (batch[mid] < g) lo = mid + 1; else hi = mid; }
  gptr[g] = lo;
}

__global__ __launch_bounds__(1024) void scan_kernel(const int* __restrict__ cnt,
                                                    int* __restrict__ row_ptr,
                                                    int* __restrict__ cursor) {
  __shared__ int wsum[16];
  int tid = threadIdx.x, lane = tid & 63, wid = tid >> 6;
  int carry = 0;
  for (int base = 0; base < N_NODES; base += 1024) {
    int idx = base + tid;
    int v = (idx < N_NODES) ? cnt[idx] : 0;
    int x = v;
#pragma unroll
    for (int off = 1; off < 64; off <<= 1) {
      int t = __shfl_up(x, off, 64);
      if (lane >= off) x += t;
    }
    if (lane == 63) wsum[wid] = x;
    __syncthreads();
    int wo = 0, tot = 0;
#pragma unroll
    for (int w = 0; w < 16; ++w) { int s = wsum[w]; tot += s; if (w < wid) wo += s; }
    int inc = x + wo + carry;
    if (idx < N_NODES) { row_ptr[idx + 1] = inc; cursor[idx] = inc - v; }
    carry += tot;
    __syncthreads();
  }
  if (tid == 0) row_ptr[0] = 0;
}

__global__ void dinv_kernel(const int* __restrict__ cnt, float* __restrict__ dinv) {
  int i = blockIdx.x * blockDim.x + threadIdx.x;
  if (i < N_NODES) dinv[i] = 1.0f / sqrtf((float)(cnt[i] + 1));
}

__global__ void scatter_kernel(const int* __restrict__ src, const int* __restrict__ dst,
                               const float* __restrict__ dinv, int* __restrict__ cursor,
                               int* __restrict__ col, float* __restrict__ ew) {
  int e = blockIdx.x * blockDim.x + threadIdx.x;
  if (e >= N_EDGES) return;
  int s = src[e], d = dst[e];
  int pos = atomicAdd(&cursor[d], 1);
  col[pos] = s;
  ew[pos] = dinv[s] * dinv[d];
}

// ---------------- weight convert + transpose: W[K][Nc] -> Wt[Nc][K] bf16 ----------------

__global__ void wconv_kernel(const float* __restrict__ W, short* __restrict__ Wt, int K, int Nc) {
  int i = blockIdx.x * blockDim.x + threadIdx.x;
  if (i >= K * Nc) return;
  int k = i / Nc, n = i - k * Nc;
  Wt[(size_t)n * K + k] = f2b(W[i]);
}

// ---------------- logmap0 (wave per row of 128) ----------------

__global__ __launch_bounds__(256) void logmap_kernel(const float* __restrict__ x,
                                                     float* __restrict__ out) {
  int row = blockIdx.x * 4 + (threadIdx.x >> 6);
  int lane = threadIdx.x & 63;
  if (row >= N_NODES) return;
  float2 v = *(const float2*)(x + (size_t)row * F_IN + lane * 2);
  float s = wave_reduce_sum(v.x * v.x + v.y * v.y);
  float n = sqrtf(s);
  float nc = fmaxf(n, 1e-15f);
  float f = atanhf(fminf(nc, 0.9999999f)) / nc;
  float2 o; o.x = v.x * f; o.y = v.y * f;
  *(float2*)(out + (size_t)row * F_IN + lane * 2) = o;
}

// ---------------- generic fp32 tiled GEMM: C[N,M] = A[N,K] @ B[K,M] ----------------

#define BM 64
#define BN 128
#define BK 32

__global__ __launch_bounds__(256) void gemm_kernel(const float* __restrict__ A, int lda,
                                                   const float* __restrict__ B, int M, int K,
                                                   int Nrows, const float* __restrict__ bias,
                                                   int do_relu, float* __restrict__ C) {
  __shared__ __align__(16) float As[BK][BM + 4];  // transposed: As[k][r]
  __shared__ __align__(16) float Bs[BK][BN + 4];
  int tid = threadIdx.x;
  int tx = tid & 15, ty = tid >> 4;
  int row0 = blockIdx.x * BM, col0 = blockIdx.y * BN;
  float acc[4][8] = {};
  for (int k0 = 0; k0 < K; k0 += BK) {
    {
      int r = tid >> 3;             // 0..31
      int kk = (tid & 7) << 2;      // 0,4,..,28
#pragma unroll
      for (int p = 0; p < 2; ++p) {
        int rr = r + p * 32;
        int gr = row0 + rr;
        float4 v = make_float4(0.f, 0.f, 0.f, 0.f);
        if (gr < Nrows) v = *(const float4*)(A + (size_t)gr * lda + k0 + kk);
        As[kk + 0][rr] = v.x; As[kk + 1][rr] = v.y; As[kk + 2][rr] = v.z; As[kk + 3][rr] = v.w;
      }
    }
    {
      int kb = tid >> 5;            // 0..7
      int c = (tid & 31) << 2;      // 0..124
#pragma unroll
      for (int p = 0; p < 4; ++p) {
        int k = kb + p * 8;
        *(float4*)&Bs[k][c] = *(const float4*)(B + (size_t)(k0 + k) * M + col0 + c);
      }
    }
    __syncthreads();
#pragma unroll
    for (int k = 0; k < BK; ++k) {
      float4 a = *(const float4*)&As[k][ty << 2];
      float4 b0 = *(const float4*)&Bs[k][tx << 2];            // 2-way bank alias: free
      float4 b1 = *(const float4*)&Bs[k][64 + (tx << 2)];
      float av[4] = {a.x, a.y, a.z, a.w};
      float bv[8] = {b0.x, b0.y, b0.z, b0.w, b1.x, b1.y, b1.z, b1.w};
#pragma unroll
      for (int i = 0; i < 4; ++i)
#pragma unroll
        for (int j = 0; j < 8; ++j) acc[i][j] = fmaf(av[i], bv[j], acc[i][j]);
    }
    __syncthreads();
  }
#pragma unroll
  for (int i = 0; i < 4; ++i) {
    int r = row0 + (ty << 2) + i;
    if (r < Nrows) {
#pragma unroll
      for (int j = 0; j < 8; ++j) {
        int c = col0 + ((j < 4) ? (tx << 2) + j : 64 + (tx << 2) + j - 4);
        float v = acc[i][j];
        if (bias) v += bias[c];
        if (do_relu) v = fmaxf(v, 0.0f);
        C[(size_t)r * M + c] = v;
      }
    }
  }
}

// ---------------- bf16 MFMA GEMM: C[M,Nc] = A[M,K] @ Bt[Nc,K]^T ----------------
// A, Bt row-major bf16 (short bit-pattern). 128x128 tile, 4 waves (2x2), each 64x64.
// Nc multiple of 128 (grid.y = Nc/128); K multiple of 32.

#define LDK 40  // 32 + 8 pad shorts

__global__ __launch_bounds__(256) void mfma_gemm_kernel(const short* __restrict__ A,
                                                        const short* __restrict__ Bt,
                                                        int M, int Nc, int K,
                                                        int do_relu,
                                                        float* __restrict__ Cf,
                                                        short* __restrict__ Cb) {
  __shared__ __align__(16) short As[128 * LDK];
  __shared__ __align__(16) short Bs[128 * LDK];
  int tid = threadIdx.x;
  int wave = tid >> 6, lane = tid & 63;
  int wr = (wave >> 1) * 64, wc = (wave & 1) * 64;
  int q = lane >> 4, m = lane & 15;
  int row0 = blockIdx.x * 128, col0 = blockIdx.y * 128;
  f32x4 acc[4][4] = {};
  for (int k0 = 0; k0 < K; k0 += 32) {
#pragma unroll
    for (int p = 0; p < 2; ++p) {
      int idx = p * 256 + tid;      // 0..511
      int r = idx >> 2, kc = (idx & 3) * 8;
      int gr = row0 + r;
      float4 v = make_float4(0.f, 0.f, 0.f, 0.f);
      if (gr < M) v = *(const float4*)(A + (size_t)gr * K + k0 + kc);
      *(float4*)(As + r * LDK + kc) = v;
      float4 w = *(const float4*)(Bt + (size_t)(col0 + r) * K + k0 + kc);
      *(float4*)(Bs + r * LDK + kc) = w;
    }
    __syncthreads();
    bf16x8 af[4], bfr[4];
#pragma unroll
    for (int i = 0; i < 4; ++i) {
      af[i]  = *(const bf16x8*)(As + (wr + i * 16 + m) * LDK + q * 8);
      bfr[i] = *(const bf16x8*)(Bs + (wc + i * 16 + m) * LDK + q * 8);
    }
#pragma unroll
    for (int i = 0; i < 4; ++i)
#pragma unroll
      for (int j = 0; j < 4; ++j)
        acc[i][j] = __builtin_amdgcn_mfma_f32_16x16x32_bf16(af[i], bfr[j], acc[i][j], 0, 0, 0);
    __syncthreads();
  }
#pragma unroll
  for (int i = 0; i < 4; ++i) {
#pragma unroll
    for (int r = 0; r < 4; ++r) {
      int rr = row0 + wr + i * 16 + q * 4 + r;
      if (rr >= M) continue;
#pragma unroll
      for (int j = 0; j < 4; ++j) {
        int cc = col0 + wc + j * 16 + m;
        float v = acc[i][j][r];
        if (do_relu) v = fmaxf(v, 0.0f);
        if (Cb) Cb[(size_t)rr * Nc + cc] = f2b(v);
        else    Cf[(size_t)rr * Nc + cc] = v;
      }
    }
  }
}

// ---------------- CSR aggregation + bias + relu; writes fp32 NB and bf16 NBb ----------------

__global__ __launch_bounds__(128) void agg_kernel(const float* __restrict__ H,
                                                  const float* __restrict__ dinv,
                                                  const int* __restrict__ row_ptr,
                                                  const int* __restrict__ col,
                                                  const float* __restrict__ ew,
                                                  const float* __restrict__ bias,
                                                  float* __restrict__ out,
                                                  short* __restrict__ outb) {
  int i = blockIdx.x;
  int c = threadIdx.x;
  float di = dinv[i];
  float acc = H[(size_t)i * D_HID + c] * (di * di);
  int s = row_ptr[i], e = row_ptr[i + 1];
  int j = s;
  for (; j + 4 <= e; j += 4) {
    int c0 = col[j], c1 = col[j + 1], c2 = col[j + 2], c3 = col[j + 3];
    float w0 = ew[j], w1 = ew[j + 1], w2 = ew[j + 2], w3 = ew[j + 3];
    acc += H[(size_t)c0 * D_HID + c] * w0;
    acc += H[(size_t)c1 * D_HID + c] * w1;
    acc += H[(size_t)c2 * D_HID + c] * w2;
    acc += H[(size_t)c3 * D_HID + c] * w3;
  }
  for (; j < e; ++j) acc += H[(size_t)col[j] * D_HID + c] * ew[j];
  acc += bias[c];
  acc = fmaxf(acc, 0.0f);
  out[(size_t)i * EDIM + c] = acc;
  outb[(size_t)i * EDIM + c] = f2b(acc);
}

// ---------------- global_add_pool over sorted batch ----------------

__global__ __launch_bounds__(384) void pool_kernel(const float* __restrict__ NB,
                                                   const int* __restrict__ gptr,
                                                   float* __restrict__ gcat_half) {
  int g = blockIdx.x, c = threadIdx.x;
  int s = gptr[g], e = gptr[g + 1];
  float acc = 0.0f;
  for (int i = s; i < e; ++i) acc += NB[(size_t)i * EDIM + c];
  gcat_half[(size_t)g * 768 + c] = acc;
}

// ---------------- expmap0 + proj, in-place on rows of 384 ----------------

__global__ __launch_bounds__(256) void exp_proj_kernel(float* __restrict__ y, int nrows) {
  int row = blockIdx.x * 4 + (threadIdx.x >> 6);
  int lane = threadIdx.x & 63;
  if (row >= nrows) return;
  float* p = y + (size_t)row * EDIM;
  float v[6];
  float s = 0.0f;
#pragma unroll
  for (int j = 0; j < 6; ++j) { v[j] = p[lane + j * 64]; s += v[j] * v[j]; }
  s = wave_reduce_sum(s);
  float n = fmaxf(sqrtf(s), 1e-15f);
  float th = tanhf(n);
  float f = th / n;
  float n2 = fmaxf(th, 1e-15f);
  const float maxn = 1.0f - 4e-3f;
  if (n2 > maxn) f *= maxn / n2;
#pragma unroll
  for (int j = 0; j < 6; ++j) p[lane + j * 64] = v[j] * f;
}

// ---------------- driver ----------------

extern "C" void kernel_launch(void* const* d_in, const int* in_sizes, int n_in,
                              void* d_out, int out_size, void* d_ws, size_t ws_size,
                              hipStream_t stream) {
  (void)in_sizes; (void)n_in; (void)out_size; (void)ws_size;
  const float* x   = (const float*)d_in[0];
  const float* x_s = (const float*)d_in[1];
  const int* src   = (const int*)d_in[2];
  const int* dst   = (const int*)d_in[3];
  const int* batch = (const int*)d_in[4];
  const float* Wf[3] = {(const float*)d_in[5], (const float*)d_in[6], (const float*)d_in[7]};
  const float* bf[3] = {(const float*)d_in[8], (const float*)d_in[9], (const float*)d_in[10]};
  const float* Wsb[3] = {(const float*)d_in[11], (const float*)d_in[12], (const float*)d_in[13]};
  const float* bs[3] = {(const float*)d_in[14], (const float*)d_in[15], (const float*)d_in[16]};
  const float* P1 = (const float*)d_in[17];
  const float* P2 = (const float*)d_in[18];
  const float* G1 = (const float*)d_in[19];
  const float* G2 = (const float*)d_in[20];
  float* out = (float*)d_out;

  char* w = (char*)d_ws;
  auto alloc = [&](size_t bytes) {
    char* p = w;
    w += (bytes + 255) & ~(size_t)255;
    return p;
  };
  float* A    = (float*)alloc((size_t)N_NODES * 128 * 4);
  float* H    = (float*)alloc((size_t)N_NODES * 128 * 4);
  float* NB   = (float*)alloc((size_t)N_NODES * 384 * 4);
  short* NBb  = (short*)alloc((size_t)N_NODES * 384 * 2);
  short* HIDb = (short*)alloc((size_t)N_NODES * 384 * 2);
  int* cnt    = (int*)alloc((size_t)N_NODES * 4);
  int* row_ptr= (int*)alloc((size_t)(N_NODES + 1) * 4);
  int* cursor = (int*)alloc((size_t)N_NODES * 4);
  float* dinv = (float*)alloc((size_t)N_NODES * 4);
  int* col    = (int*)alloc((size_t)N_EDGES * 4);
  float* ew   = (float*)alloc((size_t)N_EDGES * 4);
  int* gptr   = (int*)alloc((size_t)(N_GRAPHS + 1) * 4);
  float* gcat = (float*)alloc((size_t)N_GRAPHS * 768 * 4);
  short* P1t  = (short*)alloc((size_t)EDIM * EDIM * 2);
  short* P2t  = (short*)alloc((size_t)EDIM * EDIM * 2);

  // ---- graph structure (shared by both branches, all layers) ----
  hipMemsetAsync(cnt, 0, (size_t)N_NODES * 4, stream);
  hist_kernel<<<(N_EDGES + 255) / 256, 256, 0, stream>>>(dst, cnt);
  gptr_kernel<<<(N_GRAPHS + 256) / 256, 256, 0, stream>>>(batch, gptr);
  scan_kernel<<<1, 1024, 0, stream>>>(cnt, row_ptr, cursor);
  dinv_kernel<<<(N_NODES + 255) / 256, 256, 0, stream>>>(cnt, dinv);
  scatter_kernel<<<(N_EDGES + 255) / 256, 256, 0, stream>>>(src, dst, dinv, cursor, col, ew);
  wconv_kernel<<<(EDIM * EDIM + 255) / 256, 256, 0, stream>>>(P1, P1t, EDIM, EDIM);
  wconv_kernel<<<(EDIM * EDIM + 255) / 256, 256, 0, stream>>>(P2, P2t, EDIM, EDIM);

  const size_t OUT0 = 0;
  const size_t OUT1 = (size_t)N_GRAPHS * EDIM;
  const size_t OUT2 = OUT1 + (size_t)N_GRAPHS * EDIM;
  const size_t OUT3 = OUT2 + (size_t)N_NODES * EDIM;
  const size_t OUT4 = OUT3 + (size_t)N_GRAPHS * EDIM;

  const int gx_nodes = (N_NODES + BM - 1) / BM;       // 782
  const int gx_mfma  = (N_NODES + 127) / 128;         // 391

  auto run_branch = [&](const float* xin, const float* const* Wb, const float* const* bb,
                        float* gcat_half, float* outp) {
    logmap_kernel<<<(N_NODES + 3) / 4, 256, 0, stream>>>(xin, A);
    const float* cur = A;
    int lda = 128;
    for (int l = 0; l < 3; ++l) {
      gemm_kernel<<<dim3(gx_nodes, 1), 256, 0, stream>>>(cur, lda, Wb[l], 128, 128, N_NODES,
                                                         nullptr, 0, H);
      agg_kernel<<<N_NODES, 128, 0, stream>>>(H, dinv, row_ptr, col, ew, bb[l],
                                              NB + l * 128, NBb + l * 128);
      cur = NB + l * 128;
      lda = EDIM;
    }
    pool_kernel<<<N_GRAPHS, EDIM, 0, stream>>>(NB, gptr, gcat_half);
    // node-level MLP head in bf16 MFMA
    mfma_gemm_kernel<<<dim3(gx_mfma, 3), 256, 0, stream>>>(NBb, P1t, N_NODES, EDIM, EDIM,
                                                           1, nullptr, HIDb);
    mfma_gemm_kernel<<<dim3(gx_mfma, 3), 256, 0, stream>>>(HIDb, P2t, N_NODES, EDIM, EDIM,
                                                           0, outp, nullptr);
    exp_proj_kernel<<<(N_NODES + 3) / 4, 256, 0, stream>>>(outp, N_NODES);
  };

  run_branch(x, Wf, bf, gcat, out + OUT2);
  run_branch(x_s, Wsb, bs, gcat + EDIM, out + OUT4);

  float* GH = H;  // reuse [512,384] scratch
  const int gx_g = (N_GRAPHS + BM - 1) / BM;  // 8

  // g head: relu(gcat @ G1) @ G2 -> out0
  gemm_kernel<<<dim3(gx_g, 3), 256, 0, stream>>>(gcat, 768, G1, EDIM, 768, N_GRAPHS, nullptr, 1, GH);
  gemm_kernel<<<dim3(gx_g, 3), 256, 0, stream>>>(GH, EDIM, G2, EDIM, EDIM, N_GRAPHS, nullptr, 0, out + OUT0);
  exp_proj_kernel<<<(N_GRAPHS + 3) / 4, 256, 0, stream>>>(out + OUT0, N_GRAPHS);

  // g_f head -> out1
  gemm_kernel<<<dim3(gx_g, 3), 256, 0, stream>>>(gcat, 768, P1, EDIM, EDIM, N_GRAPHS, nullptr, 1, GH);
  gemm_kernel<<<dim3(gx_g, 3), 256, 0, stream>>>(GH, EDIM, P2, EDIM, EDIM, N_GRAPHS, nullptr, 0, out + OUT1);
  exp_proj_kernel<<<(N_GRAPHS + 3) / 4, 256, 0, stream>>>(out + OUT1, N_GRAPHS);

  // g_s head -> out3
  gemm_kernel<<<dim3(gx_g, 3), 256, 0, stream>>>(gcat + EDIM, 768, P1, EDIM, EDIM, N_GRAPHS, nullptr, 1, GH);
  gemm_kernel<<<dim3(gx_g, 3), 256, 0, stream>>>(GH, EDIM, P2, EDIM, EDIM, N_GRAPHS, nullptr, 0, out + OUT3);
  exp_proj_kernel<<<(N_GRAPHS + 3) / 4, 256, 0, stream>>>(out + OUT3, N_GRAPHS);
}

// Round 3
// 1208.969 us; speedup vs baseline: 1.7863x; 1.1701x over previous
//
#include <hip/hip_runtime.h>
#include <math.h>

#define N_NODES 50000
#define N_EDGES 600000
#define N_GRAPHS 512
#define F_IN 128
#define D_HID 128
#define EDIM 384
#define M_ALL (N_NODES + N_GRAPHS)  // node rows + appended pooled graph rows

typedef __attribute__((ext_vector_type(8))) short bf16x8;
typedef __attribute__((ext_vector_type(4))) float f32x4;

static __device__ __forceinline__ float wave_reduce_sum(float s) {
#pragma unroll
  for (int off = 32; off > 0; off >>= 1) s += __shfl_xor(s, off, 64);
  return s;
}

static __device__ __forceinline__ short f2b(float f) {
  unsigned u = __float_as_uint(f);
  unsigned r = (u + 0x7FFFu + ((u >> 16) & 1u)) >> 16;
  return (short)r;
}

// ---------------- graph preprocessing ----------------

__global__ void hist_kernel(const int* __restrict__ dst, int* __restrict__ cnt) {
  int i = blockIdx.x * blockDim.x + threadIdx.x;
  if (i < N_EDGES) atomicAdd(&cnt[dst[i]], 1);
}

__global__ void gptr_kernel(const int* __restrict__ batch, int* __restrict__ gptr) {
  int g = blockIdx.x * blockDim.x + threadIdx.x;
  if (g > N_GRAPHS) return;
  int lo = 0, hi = N_NODES;
  while (lo < hi) { int mid = (lo + hi) >> 1; if (batch[mid] < g) lo = mid + 1; else hi = mid; }
  gptr[g] = lo;
}

__global__ __launch_bounds__(1024) void scan_kernel(const int* __restrict__ cnt,
                                                    int* __restrict__ row_ptr,
                                                    int* __restrict__ cursor) {
  __shared__ int wsum[16];
  int tid = threadIdx.x, lane = tid & 63, wid = tid >> 6;
  int carry = 0;
  for (int base = 0; base < N_NODES; base += 1024) {
    int idx = base + tid;
    int v = (idx < N_NODES) ? cnt[idx] : 0;
    int x = v;
#pragma unroll
    for (int off = 1; off < 64; off <<= 1) {
      int t = __shfl_up(x, off, 64);
      if (lane >= off) x += t;
    }
    if (lane == 63) wsum[wid] = x;
    __syncthreads();
    int wo = 0, tot = 0;
#pragma unroll
    for (int w = 0; w < 16; ++w) { int s = wsum[w]; tot += s; if (w < wid) wo += s; }
    int inc = x + wo + carry;
    if (idx < N_NODES) { row_ptr[idx + 1] = inc; cursor[idx] = inc - v; }
    carry += tot;
    __syncthreads();
  }
  if (tid == 0) row_ptr[0] = 0;
}

__global__ void dinv_kernel(const int* __restrict__ cnt, float* __restrict__ dinv) {
  int i = blockIdx.x * blockDim.x + threadIdx.x;
  if (i < N_NODES) dinv[i] = 1.0f / sqrtf((float)(cnt[i] + 1));
}

__global__ void scatter_kernel(const int* __restrict__ src, const int* __restrict__ dst,
                               const float* __restrict__ dinv, int* __restrict__ cursor,
                               int* __restrict__ col, float* __restrict__ ew) {
  int e = blockIdx.x * blockDim.x + threadIdx.x;
  if (e >= N_EDGES) return;
  int s = src[e], d = dst[e];
  int pos = atomicAdd(&cursor[d], 1);
  col[pos] = s;
  ew[pos] = dinv[s] * dinv[d];
}

// ---------------- weight convert + transpose: W[K][Nc] -> Wt[Nc][K] bf16 ----------------

__global__ void wconv_kernel(const float* __restrict__ W, short* __restrict__ Wt, int K, int Nc) {
  int i = blockIdx.x * blockDim.x + threadIdx.x;
  if (i >= K * Nc) return;
  int k = i / Nc, n = i - k * Nc;
  Wt[(size_t)n * K + k] = f2b(W[i]);
}

// ---------------- logmap0 (wave per row of 128) ----------------

__global__ __launch_bounds__(256) void logmap_kernel(const float* __restrict__ x,
                                                     float* __restrict__ out) {
  int row = blockIdx.x * 4 + (threadIdx.x >> 6);
  int lane = threadIdx.x & 63;
  if (row >= N_NODES) return;
  float2 v = *(const float2*)(x + (size_t)row * F_IN + lane * 2);
  float s = wave_reduce_sum(v.x * v.x + v.y * v.y);
  float n = sqrtf(s);
  float nc = fmaxf(n, 1e-15f);
  float f = atanhf(fminf(nc, 0.9999999f)) / nc;
  float2 o; o.x = v.x * f; o.y = v.y * f;
  *(float2*)(out + (size_t)row * F_IN + lane * 2) = o;
}

// ---------------- generic fp32 tiled GEMM: C[N,M] = A[N,K] @ B[K,M] ----------------

#define BM 64
#define BN 128
#define BK 32

__global__ __launch_bounds__(256) void gemm_kernel(const float* __restrict__ A, int lda,
                                                   const float* __restrict__ B, int M, int K,
                                                   int Nrows, const float* __restrict__ bias,
                                                   int do_relu, float* __restrict__ C) {
  __shared__ __align__(16) float As[BK][BM + 4];  // transposed: As[k][r]
  __shared__ __align__(16) float Bs[BK][BN + 4];
  int tid = threadIdx.x;
  int tx = tid & 15, ty = tid >> 4;
  int row0 = blockIdx.x * BM, col0 = blockIdx.y * BN;
  float acc[4][8] = {};
  for (int k0 = 0; k0 < K; k0 += BK) {
    {
      int r = tid >> 3;             // 0..31
      int kk = (tid & 7) << 2;      // 0,4,..,28
#pragma unroll
      for (int p = 0; p < 2; ++p) {
        int rr = r + p * 32;
        int gr = row0 + rr;
        float4 v = make_float4(0.f, 0.f, 0.f, 0.f);
        if (gr < Nrows) v = *(const float4*)(A + (size_t)gr * lda + k0 + kk);
        As[kk + 0][rr] = v.x; As[kk + 1][rr] = v.y; As[kk + 2][rr] = v.z; As[kk + 3][rr] = v.w;
      }
    }
    {
      int kb = tid >> 5;            // 0..7
      int c = (tid & 31) << 2;      // 0..124
#pragma unroll
      for (int p = 0; p < 4; ++p) {
        int k = kb + p * 8;
        *(float4*)&Bs[k][c] = *(const float4*)(B + (size_t)(k0 + k) * M + col0 + c);
      }
    }
    __syncthreads();
#pragma unroll
    for (int k = 0; k < BK; ++k) {
      float4 a = *(const float4*)&As[k][ty << 2];
      float4 b0 = *(const float4*)&Bs[k][tx << 2];            // 2-way bank alias: free
      float4 b1 = *(const float4*)&Bs[k][64 + (tx << 2)];
      float av[4] = {a.x, a.y, a.z, a.w};
      float bv[8] = {b0.x, b0.y, b0.z, b0.w, b1.x, b1.y, b1.z, b1.w};
#pragma unroll
      for (int i = 0; i < 4; ++i)
#pragma unroll
        for (int j = 0; j < 8; ++j) acc[i][j] = fmaf(av[i], bv[j], acc[i][j]);
    }
    __syncthreads();
  }
#pragma unroll
  for (int i = 0; i < 4; ++i) {
    int r = row0 + (ty << 2) + i;
    if (r < Nrows) {
#pragma unroll
      for (int j = 0; j < 8; ++j) {
        int c = col0 + ((j < 4) ? (tx << 2) + j : 64 + (tx << 2) + j - 4);
        float v = acc[i][j];
        if (bias) v += bias[c];
        if (do_relu) v = fmaxf(v, 0.0f);
        C[(size_t)r * M + c] = v;
      }
    }
  }
}

// ---------------- bf16 MFMA GEMM: C[M,Nc] = A[M,K] @ Bt[Nc,K]^T ----------------
// A, Bt row-major bf16 (short bit-pattern). 128x128 tile, 4 waves (2x2), each 64x64.
// Nc multiple of 128 (grid.y = Nc/128); K multiple of 32.
// Output: bf16 to Cb if Cb != null; else fp32 row-split: rows < split -> Cf,
// rows >= split -> Cf2 + (row - split)*Nc.

#define LDK 40  // 32 + 8 pad shorts

__global__ __launch_bounds__(256) void mfma_gemm_kernel(const short* __restrict__ A,
                                                        const short* __restrict__ Bt,
                                                        int M, int Nc, int K,
                                                        int do_relu,
                                                        float* __restrict__ Cf,
                                                        float* __restrict__ Cf2, int split,
                                                        short* __restrict__ Cb) {
  __shared__ __align__(16) short As[128 * LDK];
  __shared__ __align__(16) short Bs[128 * LDK];
  int tid = threadIdx.x;
  int wave = tid >> 6, lane = tid & 63;
  int wr = (wave >> 1) * 64, wc = (wave & 1) * 64;
  int q = lane >> 4, m = lane & 15;
  int row0 = blockIdx.x * 128, col0 = blockIdx.y * 128;
  f32x4 acc[4][4] = {};
  for (int k0 = 0; k0 < K; k0 += 32) {
#pragma unroll
    for (int p = 0; p < 2; ++p) {
      int idx = p * 256 + tid;      // 0..511
      int r = idx >> 2, kc = (idx & 3) * 8;
      int gr = row0 + r;
      float4 v = make_float4(0.f, 0.f, 0.f, 0.f);
      if (gr < M) v = *(const float4*)(A + (size_t)gr * K + k0 + kc);
      *(float4*)(As + r * LDK + kc) = v;
      float4 w = *(const float4*)(Bt + (size_t)(col0 + r) * K + k0 + kc);
      *(float4*)(Bs + r * LDK + kc) = w;
    }
    __syncthreads();
    bf16x8 af[4], bfr[4];
#pragma unroll
    for (int i = 0; i < 4; ++i) {
      af[i]  = *(const bf16x8*)(As + (wr + i * 16 + m) * LDK + q * 8);
      bfr[i] = *(const bf16x8*)(Bs + (wc + i * 16 + m) * LDK + q * 8);
    }
#pragma unroll
    for (int i = 0; i < 4; ++i)
#pragma unroll
      for (int j = 0; j < 4; ++j)
        acc[i][j] = __builtin_amdgcn_mfma_f32_16x16x32_bf16(af[i], bfr[j], acc[i][j], 0, 0, 0);
    __syncthreads();
  }
#pragma unroll
  for (int i = 0; i < 4; ++i) {
#pragma unroll
    for (int r = 0; r < 4; ++r) {
      int rr = row0 + wr + i * 16 + q * 4 + r;
      if (rr >= M) continue;
#pragma unroll
      for (int j = 0; j < 4; ++j) {
        int cc = col0 + wc + j * 16 + m;
        float v = acc[i][j][r];
        if (do_relu) v = fmaxf(v, 0.0f);
        if (Cb) Cb[(size_t)rr * Nc + cc] = f2b(v);
        else if (rr < split) Cf[(size_t)rr * Nc + cc] = v;
        else Cf2[(size_t)(rr - split) * Nc + cc] = v;
      }
    }
  }
}

// ---------------- CSR aggregation + bias + relu; writes fp32 NB and bf16 NBb ----------------

__global__ __launch_bounds__(128) void agg_kernel(const float* __restrict__ H,
                                                  const float* __restrict__ dinv,
                                                  const int* __restrict__ row_ptr,
                                                  const int* __restrict__ col,
                                                  const float* __restrict__ ew,
                                                  const float* __restrict__ bias,
                                                  float* __restrict__ out,
                                                  short* __restrict__ outb) {
  int i = blockIdx.x;
  int c = threadIdx.x;
  float di = dinv[i];
  float acc = H[(size_t)i * D_HID + c] * (di * di);
  int s = row_ptr[i], e = row_ptr[i + 1];
  int j = s;
  for (; j + 4 <= e; j += 4) {
    int c0 = col[j], c1 = col[j + 1], c2 = col[j + 2], c3 = col[j + 3];
    float w0 = ew[j], w1 = ew[j + 1], w2 = ew[j + 2], w3 = ew[j + 3];
    acc += H[(size_t)c0 * D_HID + c] * w0;
    acc += H[(size_t)c1 * D_HID + c] * w1;
    acc += H[(size_t)c2 * D_HID + c] * w2;
    acc += H[(size_t)c3 * D_HID + c] * w3;
  }
  for (; j < e; ++j) acc += H[(size_t)col[j] * D_HID + c] * ew[j];
  acc += bias[c];
  acc = fmaxf(acc, 0.0f);
  out[(size_t)i * EDIM + c] = acc;
  outb[(size_t)i * EDIM + c] = f2b(acc);
}

// ---------------- global_add_pool over sorted batch ----------------
// Writes: fp32 gcat half, bf16 gcat half (for g-head GEMM input), and the
// bf16 pooled rows appended after the node rows (for the fused node+graph MLP).

__global__ __launch_bounds__(384) void pool_kernel(const float* __restrict__ NB,
                                                   const int* __restrict__ gptr,
                                                   float* __restrict__ gcat_half,
                                                   short* __restrict__ gcb_half,
                                                   short* __restrict__ nbb_append) {
  int g = blockIdx.x, c = threadIdx.x;
  int s = gptr[g], e = gptr[g + 1];
  float acc = 0.0f;
  for (int i = s; i < e; ++i) acc += NB[(size_t)i * EDIM + c];
  gcat_half[(size_t)g * 768 + c] = acc;
  gcb_half[(size_t)g * 768 + c] = f2b(acc);
  nbb_append[(size_t)g * EDIM + c] = f2b(acc);
}

// ---------------- expmap0 + proj, in-place on rows of 384 ----------------

__global__ __launch_bounds__(256) void exp_proj_kernel(float* __restrict__ y, int nrows) {
  int row = blockIdx.x * 4 + (threadIdx.x >> 6);
  int lane = threadIdx.x & 63;
  if (row >= nrows) return;
  float* p = y + (size_t)row * EDIM;
  float v[6];
  float s = 0.0f;
#pragma unroll
  for (int j = 0; j < 6; ++j) { v[j] = p[lane + j * 64]; s += v[j] * v[j]; }
  s = wave_reduce_sum(s);
  float n = fmaxf(sqrtf(s), 1e-15f);
  float th = tanhf(n);
  float f = th / n;
  float n2 = fmaxf(th, 1e-15f);
  const float maxn = 1.0f - 4e-3f;
  if (n2 > maxn) f *= maxn / n2;
#pragma unroll
  for (int j = 0; j < 6; ++j) p[lane + j * 64] = v[j] * f;
}

// ---------------- driver ----------------

extern "C" void kernel_launch(void* const* d_in, const int* in_sizes, int n_in,
                              void* d_out, int out_size, void* d_ws, size_t ws_size,
                              hipStream_t stream) {
  (void)in_sizes; (void)n_in; (void)out_size; (void)ws_size;
  const float* x   = (const float*)d_in[0];
  const float* x_s = (const float*)d_in[1];
  const int* src   = (const int*)d_in[2];
  const int* dst   = (const int*)d_in[3];
  const int* batch = (const int*)d_in[4];
  const float* Wf[3] = {(const float*)d_in[5], (const float*)d_in[6], (const float*)d_in[7]};
  const float* bf[3] = {(const float*)d_in[8], (const float*)d_in[9], (const float*)d_in[10]};
  const float* Wsb[3] = {(const float*)d_in[11], (const float*)d_in[12], (const float*)d_in[13]};
  const float* bs[3] = {(const float*)d_in[14], (const float*)d_in[15], (const float*)d_in[16]};
  const float* P1 = (const float*)d_in[17];
  const float* P2 = (const float*)d_in[18];
  const float* G1 = (const float*)d_in[19];
  const float* G2 = (const float*)d_in[20];
  float* out = (float*)d_out;

  char* w = (char*)d_ws;
  auto alloc = [&](size_t bytes) {
    char* p = w;
    w += (bytes + 255) & ~(size_t)255;
    return p;
  };
  float* A    = (float*)alloc((size_t)N_NODES * 128 * 4);
  float* H    = (float*)alloc((size_t)N_NODES * 128 * 4);
  float* NB   = (float*)alloc((size_t)N_NODES * 384 * 4);
  short* NBb  = (short*)alloc((size_t)M_ALL * 384 * 2);
  short* HIDb = (short*)alloc((size_t)M_ALL * 384 * 2);
  int* cnt    = (int*)alloc((size_t)N_NODES * 4);
  int* row_ptr= (int*)alloc((size_t)(N_NODES + 1) * 4);
  int* cursor = (int*)alloc((size_t)N_NODES * 4);
  float* dinv = (float*)alloc((size_t)N_NODES * 4);
  int* col    = (int*)alloc((size_t)N_EDGES * 4);
  float* ew   = (float*)alloc((size_t)N_EDGES * 4);
  int* gptr   = (int*)alloc((size_t)(N_GRAPHS + 1) * 4);
  float* gcat = (float*)alloc((size_t)N_GRAPHS * 768 * 4);
  short* GCb  = (short*)alloc((size_t)N_GRAPHS * 768 * 2);
  short* GHb  = (short*)alloc((size_t)N_GRAPHS * 384 * 2);
  short* P1t  = (short*)alloc((size_t)EDIM * EDIM * 2);
  short* P2t  = (short*)alloc((size_t)EDIM * EDIM * 2);
  short* G1t  = (short*)alloc((size_t)768 * EDIM * 2);
  short* G2t  = (short*)alloc((size_t)EDIM * EDIM * 2);

  // ---- graph structure (shared by both branches, all layers) ----
  hipMemsetAsync(cnt, 0, (size_t)N_NODES * 4, stream);
  hist_kernel<<<(N_EDGES + 255) / 256, 256, 0, stream>>>(dst, cnt);
  gptr_kernel<<<(N_GRAPHS + 256) / 256, 256, 0, stream>>>(batch, gptr);
  scan_kernel<<<1, 1024, 0, stream>>>(cnt, row_ptr, cursor);
  dinv_kernel<<<(N_NODES + 255) / 256, 256, 0, stream>>>(cnt, dinv);
  scatter_kernel<<<(N_EDGES + 255) / 256, 256, 0, stream>>>(src, dst, dinv, cursor, col, ew);
  wconv_kernel<<<(EDIM * EDIM + 255) / 256, 256, 0, stream>>>(P1, P1t, EDIM, EDIM);
  wconv_kernel<<<(EDIM * EDIM + 255) / 256, 256, 0, stream>>>(P2, P2t, EDIM, EDIM);
  wconv_kernel<<<(768 * EDIM + 255) / 256, 256, 0, stream>>>(G1, G1t, 768, EDIM);
  wconv_kernel<<<(EDIM * EDIM + 255) / 256, 256, 0, stream>>>(G2, G2t, EDIM, EDIM);

  const size_t OUT0 = 0;
  const size_t OUT1 = (size_t)N_GRAPHS * EDIM;
  const size_t OUT2 = OUT1 + (size_t)N_GRAPHS * EDIM;
  const size_t OUT3 = OUT2 + (size_t)N_NODES * EDIM;
  // OUT4 = OUT3 + N_GRAPHS*EDIM (contiguous after OUT3)

  const int gx_nodes = (N_NODES + BM - 1) / BM;       // 782
  const int gx_mfma  = (M_ALL + 127) / 128;           // 395

  // run one branch; ghead_out = out region for the pooled-row MLP result;
  // node_out = out region for node-level MLP result (contiguous: ghead_out
  // then node_out), so one exp_proj covers both.
  auto run_branch = [&](const float* xin, const float* const* Wb, const float* const* bb,
                        float* gcat_half, short* gcb_half, float* ghead_out, float* node_out) {
    logmap_kernel<<<(N_NODES + 3) / 4, 256, 0, stream>>>(xin, A);
    const float* cur = A;
    int lda = 128;
    for (int l = 0; l < 3; ++l) {
      gemm_kernel<<<dim3(gx_nodes, 1), 256, 0, stream>>>(cur, lda, Wb[l], 128, 128, N_NODES,
                                                         nullptr, 0, H);
      agg_kernel<<<N_NODES, 128, 0, stream>>>(H, dinv, row_ptr, col, ew, bb[l],
                                              NB + l * 128, NBb + l * 128);
      cur = NB + l * 128;
      lda = EDIM;
    }
    pool_kernel<<<N_GRAPHS, EDIM, 0, stream>>>(NB, gptr, gcat_half, gcb_half,
                                               NBb + (size_t)N_NODES * EDIM);
    // fused node+graph MLP head in bf16 MFMA (M = 50512 rows)
    mfma_gemm_kernel<<<dim3(gx_mfma, 3), 256, 0, stream>>>(NBb, P1t, M_ALL, EDIM, EDIM,
                                                           1, nullptr, nullptr, 0, HIDb);
    mfma_gemm_kernel<<<dim3(gx_mfma, 3), 256, 0, stream>>>(HIDb, P2t, M_ALL, EDIM, EDIM,
                                                           0, node_out, ghead_out, N_NODES,
                                                           nullptr);
    // ghead_out (512 rows) is contiguous with node_out (50000 rows): one pass
    exp_proj_kernel<<<(M_ALL + 3) / 4, 256, 0, stream>>>(ghead_out, M_ALL);
  };

  run_branch(x, Wf, bf, gcat, GCb, out + OUT1, out + OUT2);
  run_branch(x_s, Wsb, bs, gcat + EDIM, GCb + EDIM, out + OUT3, out + OUT3 + OUT1);

  // g head: relu(gcat @ G1) @ G2 -> out0 (bf16 MFMA, M=512)
  const int gx_g = (N_GRAPHS + 127) / 128;  // 4
  mfma_gemm_kernel<<<dim3(gx_g, 3), 256, 0, stream>>>(GCb, G1t, N_GRAPHS, EDIM, 768,
                                                      1, nullptr, nullptr, 0, GHb);
  mfma_gemm_kernel<<<dim3(gx_g, 3), 256, 0, stream>>>(GHb, G2t, N_GRAPHS, EDIM, EDIM,
                                                      0, out + OUT0, out + OUT0, 1 << 30,
                                                      nullptr);
  exp_proj_kernel<<<(N_GRAPHS + 3) / 4, 256, 0, stream>>>(out + OUT0, N_GRAPHS);
}

// Round 4
// 996.299 us; speedup vs baseline: 2.1676x; 1.2135x over previous
//
#include <hip/hip_runtime.h>
#include <math.h>

#define N_NODES 50000
#define N_EDGES 600000
#define N_GRAPHS 512
#define F_IN 128
#define D_HID 128
#define EDIM 384
#define M_ALL (N_NODES + N_GRAPHS)  // node rows + appended pooled graph rows

typedef __attribute__((ext_vector_type(8))) short bf16x8;
typedef __attribute__((ext_vector_type(4))) float f32x4;

static __device__ __forceinline__ float wave_reduce_sum(float s) {
#pragma unroll
  for (int off = 32; off > 0; off >>= 1) s += __shfl_xor(s, off, 64);
  return s;
}

static __device__ __forceinline__ short f2b(float f) {
  unsigned u = __float_as_uint(f);
  unsigned r = (u + 0x7FFFu + ((u >> 16) & 1u)) >> 16;
  return (short)r;
}

static __device__ __forceinline__ float b2f(short s) {
  return __uint_as_float(((unsigned)(unsigned short)s) << 16);
}

// ---------------- graph preprocessing ----------------

__global__ void hist_kernel(const int* __restrict__ dst, int* __restrict__ cnt) {
  int i = blockIdx.x * blockDim.x + threadIdx.x;
  if (i < N_EDGES) atomicAdd(&cnt[dst[i]], 1);
}

__global__ void gptr_kernel(const int* __restrict__ batch, int* __restrict__ gptr) {
  int g = blockIdx.x * blockDim.x + threadIdx.x;
  if (g > N_GRAPHS) return;
  int lo = 0, hi = N_NODES;
  while (lo < hi) { int mid = (lo + hi) >> 1; if (batch[mid] < g) lo = mid + 1; else hi = mid; }
  gptr[g] = lo;
}

// ---- 3-phase parallel exclusive scan of cnt -> row_ptr, cursor ----

#define SCAN_BS 256
#define SCAN_NB ((N_NODES + SCAN_BS - 1) / SCAN_BS)  // 196

__global__ __launch_bounds__(SCAN_BS) void scan1_kernel(const int* __restrict__ cnt,
                                                        int* __restrict__ row_ptr,
                                                        int* __restrict__ bsum) {
  __shared__ int wsum[4];
  int tid = threadIdx.x, lane = tid & 63, wid = tid >> 6;
  int idx = blockIdx.x * SCAN_BS + tid;
  int v = (idx < N_NODES) ? cnt[idx] : 0;
  int x = v;
#pragma unroll
  for (int off = 1; off < 64; off <<= 1) {
    int t = __shfl_up(x, off, 64);
    if (lane >= off) x += t;
  }
  if (lane == 63) wsum[wid] = x;
  __syncthreads();
  int pre = 0, tot = 0;
#pragma unroll
  for (int w = 0; w < 4; ++w) { int s = wsum[w]; tot += s; if (w < wid) pre += s; }
  if (idx < N_NODES) row_ptr[idx + 1] = x + pre;  // block-local inclusive
  if (tid == 0) bsum[blockIdx.x] = tot;
}

__global__ __launch_bounds__(SCAN_BS) void scan2_kernel(const int* __restrict__ bsum,
                                                        int* __restrict__ boffs) {
  __shared__ int wsum[4];
  int tid = threadIdx.x, lane = tid & 63, wid = tid >> 6;
  int v = (tid < SCAN_NB) ? bsum[tid] : 0;
  int x = v;
#pragma unroll
  for (int off = 1; off < 64; off <<= 1) {
    int t = __shfl_up(x, off, 64);
    if (lane >= off) x += t;
  }
  if (lane == 63) wsum[wid] = x;
  __syncthreads();
  int pre = 0;
#pragma unroll
  for (int w = 0; w < 4; ++w) { int s = wsum[w]; if (w < wid) pre += s; }
  if (tid < SCAN_NB) boffs[tid] = x + pre - v;  // exclusive
}

__global__ __launch_bounds__(SCAN_BS) void scan3_kernel(const int* __restrict__ cnt,
                                                        const int* __restrict__ boffs,
                                                        int* __restrict__ row_ptr,
                                                        int* __restrict__ cursor) {
  int idx = blockIdx.x * SCAN_BS + threadIdx.x;
  if (idx >= N_NODES) return;
  int val = row_ptr[idx + 1] + boffs[blockIdx.x];
  row_ptr[idx + 1] = val;
  cursor[idx] = val - cnt[idx];
  if (idx == 0) row_ptr[0] = 0;
}

__global__ void dinv_kernel(const int* __restrict__ cnt, float* __restrict__ dinv) {
  int i = blockIdx.x * blockDim.x + threadIdx.x;
  if (i < N_NODES) dinv[i] = 1.0f / sqrtf((float)(cnt[i] + 1));
}

__global__ void scatter_kernel(const int* __restrict__ src, const int* __restrict__ dst,
                               const float* __restrict__ dinv, int* __restrict__ cursor,
                               int* __restrict__ col, float* __restrict__ ew) {
  int e = blockIdx.x * blockDim.x + threadIdx.x;
  if (e >= N_EDGES) return;
  int s = src[e], d = dst[e];
  int pos = atomicAdd(&cursor[d], 1);
  col[pos] = s;
  ew[pos] = dinv[s] * dinv[d];
}

// ---------------- combined weight convert+transpose (10 matrices, 1 launch) ----

struct WcSeg { const float* W; short* Wt; int K; int Nc; };
struct WcArgs { WcSeg seg[10]; };

__global__ void wconv_all_kernel(WcArgs a) {
  int sidx = blockIdx.y;
  WcSeg s = a.seg[sidx];
  int i = blockIdx.x * blockDim.x + threadIdx.x;
  if (i >= s.K * s.Nc) return;
  int k = i / s.Nc, n = i - k * s.Nc;
  s.Wt[(size_t)n * s.K + k] = f2b(s.W[i]);
}

// ---------------- logmap0 (wave per row of 128) -> bf16 ----------------

__global__ __launch_bounds__(256) void logmap_kernel(const float* __restrict__ x,
                                                     short* __restrict__ out) {
  int row = blockIdx.x * 4 + (threadIdx.x >> 6);
  int lane = threadIdx.x & 63;
  if (row >= N_NODES) return;
  float2 v = *(const float2*)(x + (size_t)row * F_IN + lane * 2);
  float s = wave_reduce_sum(v.x * v.x + v.y * v.y);
  float n = sqrtf(s);
  float nc = fmaxf(n, 1e-15f);
  float f = atanhf(fminf(nc, 0.9999999f)) / nc;
  short2 o; o.x = f2b(v.x * f); o.y = f2b(v.y * f);
  *(short2*)(out + (size_t)row * F_IN + lane * 2) = o;
}

// ---------------- bf16 MFMA GEMM: C[M,Nc] = A[M,K] @ Bt[Nc,K]^T ----------------
// A row stride lda (shorts); Bt row-major [Nc][K]. 128x128 tile, 4 waves (2x2).
// Nc multiple of 128; K multiple of 32.
// Output stride Nc: bf16 to Cb if Cb != null; else fp32 row-split:
// rows < split -> Cf, rows >= split -> Cf2 + (row - split)*Nc.

#define LDK 40  // 32 + 8 pad shorts

__global__ __launch_bounds__(256) void mfma_gemm_kernel(const short* __restrict__ A, int lda,
                                                        const short* __restrict__ Bt,
                                                        int M, int Nc, int K,
                                                        int do_relu,
                                                        float* __restrict__ Cf,
                                                        float* __restrict__ Cf2, int split,
                                                        short* __restrict__ Cb) {
  __shared__ __align__(16) short As[128 * LDK];
  __shared__ __align__(16) short Bs[128 * LDK];
  int tid = threadIdx.x;
  int wave = tid >> 6, lane = tid & 63;
  int wr = (wave >> 1) * 64, wc = (wave & 1) * 64;
  int q = lane >> 4, m = lane & 15;
  int row0 = blockIdx.x * 128, col0 = blockIdx.y * 128;
  f32x4 acc[4][4] = {};
  for (int k0 = 0; k0 < K; k0 += 32) {
#pragma unroll
    for (int p = 0; p < 2; ++p) {
      int idx = p * 256 + tid;      // 0..511
      int r = idx >> 2, kc = (idx & 3) * 8;
      int gr = row0 + r;
      float4 v = make_float4(0.f, 0.f, 0.f, 0.f);
      if (gr < M) v = *(const float4*)(A + (size_t)gr * lda + k0 + kc);
      *(float4*)(As + r * LDK + kc) = v;
      float4 w = *(const float4*)(Bt + (size_t)(col0 + r) * K + k0 + kc);
      *(float4*)(Bs + r * LDK + kc) = w;
    }
    __syncthreads();
    bf16x8 af[4], bfr[4];
#pragma unroll
    for (int i = 0; i < 4; ++i) {
      af[i]  = *(const bf16x8*)(As + (wr + i * 16 + m) * LDK + q * 8);
      bfr[i] = *(const bf16x8*)(Bs + (wc + i * 16 + m) * LDK + q * 8);
    }
#pragma unroll
    for (int i = 0; i < 4; ++i)
#pragma unroll
      for (int j = 0; j < 4; ++j)
        acc[i][j] = __builtin_amdgcn_mfma_f32_16x16x32_bf16(af[i], bfr[j], acc[i][j], 0, 0, 0);
    __syncthreads();
  }
#pragma unroll
  for (int i = 0; i < 4; ++i) {
#pragma unroll
    for (int r = 0; r < 4; ++r) {
      int rr = row0 + wr + i * 16 + q * 4 + r;
      if (rr >= M) continue;
#pragma unroll
      for (int j = 0; j < 4; ++j) {
        int cc = col0 + wc + j * 16 + m;
        float v = acc[i][j][r];
        if (do_relu) v = fmaxf(v, 0.0f);
        if (Cb) Cb[(size_t)rr * Nc + cc] = f2b(v);
        else if (rr < split) Cf[(size_t)rr * Nc + cc] = v;
        else Cf2[(size_t)(rr - split) * Nc + cc] = v;
      }
    }
  }
}

// ---------------- CSR aggregation + bias + relu; fp32 in, bf16 out ----------------

__global__ __launch_bounds__(128) void agg_kernel(const float* __restrict__ H,
                                                  const float* __restrict__ dinv,
                                                  const int* __restrict__ row_ptr,
                                                  const int* __restrict__ col,
                                                  const float* __restrict__ ew,
                                                  const float* __restrict__ bias,
                                                  short* __restrict__ outb) {
  int i = blockIdx.x;
  int c = threadIdx.x;
  float di = dinv[i];
  float acc = H[(size_t)i * D_HID + c] * (di * di);
  int s = row_ptr[i], e = row_ptr[i + 1];
  int j = s;
  for (; j + 4 <= e; j += 4) {
    int c0 = col[j], c1 = col[j + 1], c2 = col[j + 2], c3 = col[j + 3];
    float w0 = ew[j], w1 = ew[j + 1], w2 = ew[j + 2], w3 = ew[j + 3];
    acc += H[(size_t)c0 * D_HID + c] * w0;
    acc += H[(size_t)c1 * D_HID + c] * w1;
    acc += H[(size_t)c2 * D_HID + c] * w2;
    acc += H[(size_t)c3 * D_HID + c] * w3;
  }
  for (; j < e; ++j) acc += H[(size_t)col[j] * D_HID + c] * ew[j];
  acc += bias[c];
  acc = fmaxf(acc, 0.0f);
  outb[(size_t)i * EDIM + c] = f2b(acc);
}

// ---------------- global_add_pool over sorted batch (bf16 in, bf16 out) ----------

__global__ __launch_bounds__(384) void pool_kernel(const short* __restrict__ NBb,
                                                   const int* __restrict__ gptr,
                                                   short* __restrict__ gcb_half,
                                                   short* __restrict__ nbb_append) {
  int g = blockIdx.x, c = threadIdx.x;
  int s = gptr[g], e = gptr[g + 1];
  float acc = 0.0f;
  for (int i = s; i < e; ++i) acc += b2f(NBb[(size_t)i * EDIM + c]);
  short bv = f2b(acc);
  gcb_half[(size_t)g * 768 + c] = bv;
  nbb_append[(size_t)g * EDIM + c] = bv;
}

// ---------------- expmap0 + proj, in-place on rows of 384 ----------------

__global__ __launch_bounds__(256) void exp_proj_kernel(float* __restrict__ y, int nrows) {
  int row = blockIdx.x * 4 + (threadIdx.x >> 6);
  int lane = threadIdx.x & 63;
  if (row >= nrows) return;
  float* p = y + (size_t)row * EDIM;
  float v[6];
  float s = 0.0f;
#pragma unroll
  for (int j = 0; j < 6; ++j) { v[j] = p[lane + j * 64]; s += v[j] * v[j]; }
  s = wave_reduce_sum(s);
  float n = fmaxf(sqrtf(s), 1e-15f);
  float th = tanhf(n);
  float f = th / n;
  float n2 = fmaxf(th, 1e-15f);
  const float maxn = 1.0f - 4e-3f;
  if (n2 > maxn) f *= maxn / n2;
#pragma unroll
  for (int j = 0; j < 6; ++j) p[lane + j * 64] = v[j] * f;
}

// ---------------- driver ----------------

extern "C" void kernel_launch(void* const* d_in, const int* in_sizes, int n_in,
                              void* d_out, int out_size, void* d_ws, size_t ws_size,
                              hipStream_t stream) {
  (void)in_sizes; (void)n_in; (void)out_size; (void)ws_size;
  const float* x   = (const float*)d_in[0];
  const float* x_s = (const float*)d_in[1];
  const int* src   = (const int*)d_in[2];
  const int* dst   = (const int*)d_in[3];
  const int* batch = (const int*)d_in[4];
  const float* Wf[3] = {(const float*)d_in[5], (const float*)d_in[6], (const float*)d_in[7]};
  const float* bf[3] = {(const float*)d_in[8], (const float*)d_in[9], (const float*)d_in[10]};
  const float* Wsb[3] = {(const float*)d_in[11], (const float*)d_in[12], (const float*)d_in[13]};
  const float* bs[3] = {(const float*)d_in[14], (const float*)d_in[15], (const float*)d_in[16]};
  const float* P1 = (const float*)d_in[17];
  const float* P2 = (const float*)d_in[18];
  const float* G1 = (const float*)d_in[19];
  const float* G2 = (const float*)d_in[20];
  float* out = (float*)d_out;

  char* w = (char*)d_ws;
  auto alloc = [&](size_t bytes) {
    char* p = w;
    w += (bytes + 255) & ~(size_t)255;
    return p;
  };
  short* Ab   = (short*)alloc((size_t)N_NODES * 128 * 2);
  float* H    = (float*)alloc((size_t)N_NODES * 128 * 4);
  short* NBb  = (short*)alloc((size_t)M_ALL * 384 * 2);
  short* HIDb = (short*)alloc((size_t)M_ALL * 384 * 2);
  int* cnt    = (int*)alloc((size_t)N_NODES * 4);
  int* row_ptr= (int*)alloc((size_t)(N_NODES + 1) * 4);
  int* cursor = (int*)alloc((size_t)N_NODES * 4);
  float* dinv = (float*)alloc((size_t)N_NODES * 4);
  int* col    = (int*)alloc((size_t)N_EDGES * 4);
  float* ew   = (float*)alloc((size_t)N_EDGES * 4);
  int* gptr   = (int*)alloc((size_t)(N_GRAPHS + 1) * 4);
  int* bsum   = (int*)alloc(256 * 4);
  int* boffs  = (int*)alloc(256 * 4);
  short* GCb  = (short*)alloc((size_t)N_GRAPHS * 768 * 2);
  short* GHb  = (short*)alloc((size_t)N_GRAPHS * 384 * 2);
  short* P1t  = (short*)alloc((size_t)EDIM * EDIM * 2);
  short* P2t  = (short*)alloc((size_t)EDIM * EDIM * 2);
  short* G1t  = (short*)alloc((size_t)768 * EDIM * 2);
  short* G2t  = (short*)alloc((size_t)EDIM * EDIM * 2);
  short* Wft[3], *Wst[3];
  for (int l = 0; l < 3; ++l) {
    Wft[l] = (short*)alloc((size_t)128 * 128 * 2);
    Wst[l] = (short*)alloc((size_t)128 * 128 * 2);
  }

  // ---- graph structure (shared by both branches, all layers) ----
  hipMemsetAsync(cnt, 0, (size_t)N_NODES * 4, stream);
  hist_kernel<<<(N_EDGES + 255) / 256, 256, 0, stream>>>(dst, cnt);
  gptr_kernel<<<(N_GRAPHS + 256) / 256, 256, 0, stream>>>(batch, gptr);
  scan1_kernel<<<SCAN_NB, SCAN_BS, 0, stream>>>(cnt, row_ptr, bsum);
  scan2_kernel<<<1, SCAN_BS, 0, stream>>>(bsum, boffs);
  scan3_kernel<<<SCAN_NB, SCAN_BS, 0, stream>>>(cnt, boffs, row_ptr, cursor);
  dinv_kernel<<<(N_NODES + 255) / 256, 256, 0, stream>>>(cnt, dinv);
  scatter_kernel<<<(N_EDGES + 255) / 256, 256, 0, stream>>>(src, dst, dinv, cursor, col, ew);

  {
    WcArgs wa;
    wa.seg[0] = {P1, P1t, EDIM, EDIM};
    wa.seg[1] = {P2, P2t, EDIM, EDIM};
    wa.seg[2] = {G1, G1t, 768, EDIM};
    wa.seg[3] = {G2, G2t, EDIM, EDIM};
    for (int l = 0; l < 3; ++l) {
      wa.seg[4 + l] = {Wf[l], Wft[l], 128, 128};
      wa.seg[7 + l] = {Wsb[l], Wst[l], 128, 128};
    }
    wconv_all_kernel<<<dim3((768 * EDIM + 255) / 256, 10), 256, 0, stream>>>(wa);
  }

  const size_t OUT0 = 0;
  const size_t OUT1 = (size_t)N_GRAPHS * EDIM;
  const size_t OUT2 = OUT1 + (size_t)N_GRAPHS * EDIM;
  const size_t OUT3 = OUT2 + (size_t)N_NODES * EDIM;

  const int gx_layer = (N_NODES + 127) / 128;   // 391
  const int gx_mfma  = (M_ALL + 127) / 128;     // 395

  auto run_branch = [&](const float* xin, short* const* Wt, const float* const* bb,
                        short* gcb_half, float* ghead_out, float* node_out) {
    logmap_kernel<<<(N_NODES + 3) / 4, 256, 0, stream>>>(xin, Ab);
    const short* cur = Ab;
    int lda = 128;
    for (int l = 0; l < 3; ++l) {
      mfma_gemm_kernel<<<dim3(gx_layer, 1), 256, 0, stream>>>(cur, lda, Wt[l], N_NODES, 128, 128,
                                                              0, H, nullptr, 1 << 30, nullptr);
      agg_kernel<<<N_NODES, 128, 0, stream>>>(H, dinv, row_ptr, col, ew, bb[l], NBb + l * 128);
      cur = NBb + l * 128;
      lda = EDIM;
    }
    pool_kernel<<<N_GRAPHS, EDIM, 0, stream>>>(NBb, gptr, gcb_half,
                                               NBb + (size_t)N_NODES * EDIM);
    // fused node+graph MLP head (M = 50512 rows)
    mfma_gemm_kernel<<<dim3(gx_mfma, 3), 256, 0, stream>>>(NBb, EDIM, P1t, M_ALL, EDIM, EDIM,
                                                           1, nullptr, nullptr, 0, HIDb);
    mfma_gemm_kernel<<<dim3(gx_mfma, 3), 256, 0, stream>>>(HIDb, EDIM, P2t, M_ALL, EDIM, EDIM,
                                                           0, node_out, ghead_out, N_NODES,
                                                           nullptr);
    exp_proj_kernel<<<(M_ALL + 3) / 4, 256, 0, stream>>>(ghead_out, M_ALL);
  };

  run_branch(x, Wft, bf, GCb, out + OUT1, out + OUT2);
  run_branch(x_s, Wst, bs, GCb + EDIM, out + OUT3, out + OUT3 + OUT1);

  // g head: relu(gcat @ G1) @ G2 -> out0 (bf16 MFMA, M=512)
  const int gx_g = (N_GRAPHS + 127) / 128;  // 4
  mfma_gemm_kernel<<<dim3(gx_g, 3), 256, 0, stream>>>(GCb, 768, G1t, N_GRAPHS, EDIM, 768,
                                                      1, nullptr, nullptr, 0, GHb);
  mfma_gemm_kernel<<<dim3(gx_g, 3), 256, 0, stream>>>(GHb, EDIM, G2t, N_GRAPHS, EDIM, EDIM,
                                                      0, out + OUT0, out + OUT0, 1 << 30,
                                                      nullptr);
  exp_proj_kernel<<<(N_GRAPHS + 3) / 4, 256, 0, stream>>>(out + OUT0, N_GRAPHS);
}